// Round 12
// baseline (87.513 us; speedup 1.0000x reference)
//
#include <hip/hip_runtime.h>
#include <hip/hip_bf16.h>

// LinearCombiner: MLP has NO activation -> affine: out = M@x + c,
// M = W3@W2@W1 (8x3072), c = (W3@W2)@b1 + W3@b2 + b3, and
// x[t,u] = [min;max;user] separable -> out[t,u,o] = P[t,o]+Q[u,o]+c[o].
//
// 3 kernels (ledger: each kernel boundary ~2.5us dispatch overhead):
//  K1 (24x32): part1 = W3@W2 k-slice partials + cp2 ; zeroes tail counter
//  K2 (24x32): self-reduce M2 slice from part1 (L2-hot), part2 = M2@W1 + cp1;
//              then decoupled-counter tail: release fetch_add -> last 160
//              incrementers spin (acquire) until all 768 wrote part2, then
//              each runs one K3 item: items 0..127 Mt-chunk reduce,
//              items 128..159 M_user chunk reduce + user projection -> Qpart.
//              (rocPRIM decoupled-lookback pattern; deadlock-free: every
//              block increments before any spin; spinners 160 << grid.)
//  K3 (256):   P[t] from Mt + Q = sum Qpart + c (inline from cp1/cp2) -> out.

#define HIDN 3072
#define DIM 1024
#define NOUT 8
#define NS 32            // k-slices
#define KPS 96           // rows per slice
#define RPT 12           // rows per thread (KPS / 8 row-groups)
#define GX 24            // column groups of 128 cols
#define CPB 128          // cols per block (32 f4)
#define TDIM 256
#define UDIM 128
#define PF4 6144         // NOUT*HIDN/4 (f4 stride between slice partials)
#define NBLK2 768        // GX*NS
#define NTAIL 160        // 128 Mt items + 32 Q items
#define TAIL0 (NBLK2 - NTAIL)

__device__ __forceinline__ float4 f4z() { return make_float4(0.f, 0.f, 0.f, 0.f); }
__device__ __forceinline__ float4 add4(float4 a, float4 b) {
    return make_float4(a.x + b.x, a.y + b.y, a.z + b.z, a.w + b.w);
}
__device__ __forceinline__ float dot4(float4 a, float4 b) {
    return a.x * b.x + a.y * b.y + a.z * b.z + a.w * b.w;
}

// fold cp[s][o] = sum_kk As[o][kk] * bvec[s*KPS+kk]  (32 lanes per o)
__device__ __forceinline__ void bias_slice_fold(const float* As,
                                                const float* __restrict__ bvec,
                                                float* __restrict__ cp,
                                                int s, int tid) {
    const int o = tid >> 5, k5 = tid & 31;
    float acc = 0.f;
#pragma unroll
    for (int j = 0; j < KPS / 32; ++j)
        acc += As[o * KPS + k5 + 32 * j] * bvec[s * KPS + k5 + 32 * j];
#pragma unroll
    for (int off = 16; off; off >>= 1) acc += __shfl_down(acc, off, 32);
    if (k5 == 0) cp[s * NOUT + o] = acc;
}

// tail item b in [0,128): Mt chunk reduce (32 f4)
__device__ __forceinline__ void tail_mt(const float4* __restrict__ p4,
                                        float* __restrict__ Mt,
                                        int b, int tid, float4* redls) {
    const int li = tid & 31, sg = tid >> 5;
    const int i4 = b * 32 + li;                  // [0,4096): o=i4>>9, h4=i4&511
    const int o = i4 >> 9, h4 = i4 & 511;
    float4 acc = f4z();
#pragma unroll
    for (int j = 0; j < 4; ++j)
        acc = add4(acc, p4[(size_t)(sg * 4 + j) * PF4 + o * 768 + h4]);
    redls[sg * 32 + li] = acc;
    __syncthreads();
    if (tid < 32) {
        float4 r = f4z();
#pragma unroll
        for (int q = 0; q < 8; ++q) r = add4(r, redls[q * 32 + tid]);
        ((float4*)Mt)[b * 32 + tid] = r;
    }
}

// tail item ub in [0,32): M_user 32-dim chunk reduce + projection vs user
__device__ __forceinline__ void tail_q(const float4* __restrict__ p4,
                                       const float* __restrict__ user,
                                       float* __restrict__ Qpart,
                                       int ub, int tid, float4* redls) {
    float4* mup = redls;                         // 256 f4
    float4* Mu4 = redls + 256;                   // 64 f4
    const int tgt = tid & 63, grp = tid >> 6;
    const int o = tgt >> 3, j4 = tgt & 7;
    float4 a = f4z();
#pragma unroll
    for (int j = 0; j < 8; ++j)
        a = add4(a, p4[(size_t)(grp * 8 + j) * PF4 + o * 768 + 512 + ub * 8 + j4]);
    mup[grp * 64 + tgt] = a;
    __syncthreads();
    if (tid < 64)
        Mu4[tid] = add4(add4(mup[tid], mup[64 + tid]),
                        add4(mup[128 + tid], mup[192 + tid]));
    __syncthreads();

    const int u = tid >> 1, o0 = (tid & 1) * 4;
    const float4* uv = (const float4*)user + (size_t)u * (DIM / 4) + ub * 8;
    float4 x8[8];
#pragma unroll
    for (int j = 0; j < 8; ++j) x8[j] = uv[j];
    float q[4];
#pragma unroll
    for (int oo = 0; oo < 4; ++oo) {
        float s = 0.f;
#pragma unroll
        for (int j = 0; j < 8; ++j) s += dot4(Mu4[(o0 + oo) * 8 + j], x8[j]);
        q[oo] = s;
    }
    ((float4*)Qpart)[((size_t)ub * UDIM + u) * 2 + (tid & 1)] =
        make_float4(q[0], q[1], q[2], q[3]);
}

// mode 0 (K1): A_rows read directly; zeroes ctr. mode 1 (K2): A slice
// self-reduced from part_in; decoupled-counter tail absorbs old K3.
// Block: 96 rows x 128 cols. Thread: rq = tid>>5 (12 rows), c4 = tid&31.
__global__ __launch_bounds__(256) void gemm_partial(
    const float* __restrict__ A_rows, const float* __restrict__ part_in,
    const float* __restrict__ B, float* __restrict__ part_out,
    const float* __restrict__ bvec, float* __restrict__ cp,
    const float* __restrict__ user, float* __restrict__ Mt,
    float* __restrict__ Qpart, int* __restrict__ ctr, int mode) {
    const int s = blockIdx.y, gx = blockIdx.x;
    const int tid = threadIdx.x;
    const int rq = tid >> 5, c4 = tid & 31;

    __shared__ float As[NOUT * KPS];          // 3 KB
    __shared__ float4 red[8 * NOUT * 32];     // 32 KB: [rq][o][c4]

    if (mode == 0) {
        if (s == 0 && gx == 0 && tid == 0) *ctr = 0;   // reset tail counter
        for (int i = tid; i < NOUT * KPS; i += 256)
            As[i] = A_rows[(i / KPS) * HIDN + s * KPS + (i % KPS)];
    } else {
        // As[o][kk] = sum_sp part_in[sp][o][s*KPS+kk]  (L2/L3-hot, f4)
        if (tid < NOUT * KPS / 4) {
            const int j4 = tid;
            const int o = j4 / (KPS / 4), kk4 = j4 % (KPS / 4);
            const float4* pp = (const float4*)(part_in + (size_t)o * HIDN
                                               + s * KPS) + kk4;
            float4 a = f4z();
#pragma unroll 8
            for (int sp = 0; sp < NS; ++sp)
                a = add4(a, pp[(size_t)sp * PF4]);
            ((float4*)As)[j4] = a;
        }
    }
    __syncthreads();
    if (gx == 0) bias_slice_fold(As, bvec, cp, s, tid);

    const int k0 = s * KPS + rq * RPT;
    const float4* Bp = (const float4*)(B + (size_t)k0 * HIDN) + gx * 32 + c4;

    float4 bv[RPT];                            // 12 hoisted loads, 12KB/wave
#pragma unroll
    for (int kk = 0; kk < RPT; ++kk) bv[kk] = Bp[(size_t)kk * (HIDN / 4)];

    float4 acc[NOUT];
#pragma unroll
    for (int o = 0; o < NOUT; ++o) acc[o] = f4z();
#pragma unroll
    for (int kk = 0; kk < RPT; ++kk) {
#pragma unroll
        for (int o = 0; o < NOUT; ++o) {
            float a = As[o * KPS + rq * RPT + kk];
            acc[o].x += a * bv[kk].x; acc[o].y += a * bv[kk].y;
            acc[o].z += a * bv[kk].z; acc[o].w += a * bv[kk].w;
        }
    }

    // cross-row-group reduce: red[rq][o][c4], then thread (o,c4) sums 8 rq
#pragma unroll
    for (int o = 0; o < NOUT; ++o) red[rq * 256 + o * 32 + c4] = acc[o];
    __syncthreads();
    {
        const int o = tid >> 5, cc = tid & 31;   // 256 threads = 8 o x 32 c4
        float4 r = f4z();
#pragma unroll
        for (int q = 0; q < 8; ++q) r = add4(r, red[q * 256 + o * 32 + cc]);
        *(float4*)(part_out + ((size_t)s * NOUT + o) * HIDN + gx * CPB + cc * 4) = r;
    }

    if (mode == 0) return;

    // ---- decoupled tail: last NTAIL incrementers absorb old K3 ----
    __shared__ int item_s;
    __syncthreads();                          // part_out store issued by all
    if (tid == 0) {
        // release: prior part_out stores visible before the increment lands
        int old = __hip_atomic_fetch_add(ctr, 1, __ATOMIC_ACQ_REL,
                                         __HIP_MEMORY_SCOPE_AGENT);
        int item = old - TAIL0;
        if (item >= 0) {
            while (__hip_atomic_load(ctr, __ATOMIC_ACQUIRE,
                                     __HIP_MEMORY_SCOPE_AGENT) < NBLK2) { }
        }
        item_s = item;
    }
    __syncthreads();
    const int item = item_s;
    if (item < 0) return;
    __threadfence();                          // acquire: invalidate stale lines

    const float4* p4 = (const float4*)part_out;
    if (item < 128) tail_mt(p4, Mt, item, tid, red);
    else           tail_q(p4, user, Qpart, item - 128, tid, red);
}

// K3 (out): out[t,u,:] = P[t] + sum_ub Qpart[ub][u] + c   (256 t-blocks)
__global__ __launch_bounds__(256) void k4_out(
    const float* __restrict__ ta, const float* __restrict__ tb,
    const float* __restrict__ Mt, const float* __restrict__ Qpart,
    const float* __restrict__ cp1, const float* __restrict__ cp2,
    const float* __restrict__ b3, float4* __restrict__ out) {
    const int t = blockIdx.x, tid = threadIdx.x;
    const int lane = tid & 63, w = tid >> 6;

    const float4* Mt4 = (const float4*)Mt;
    float4 a = ((const float4*)ta)[(size_t)t * (DIM / 4) + tid];
    float4 b = ((const float4*)tb)[(size_t)t * (DIM / 4) + tid];
    float4 mn = make_float4(fminf(a.x, b.x), fminf(a.y, b.y),
                            fminf(a.z, b.z), fminf(a.w, b.w));
    float4 mx = make_float4(fmaxf(a.x, b.x), fmaxf(a.y, b.y),
                            fmaxf(a.z, b.z), fmaxf(a.w, b.w));
    float acc[NOUT];
#pragma unroll
    for (int o = 0; o < NOUT; ++o) {
        float4 ml = Mt4[o * 512 + tid];          // dims 0..1023 (min half)
        float4 mh = Mt4[o * 512 + 256 + tid];    // dims 1024..2047 (max half)
        acc[o] = dot4(ml, mn) + dot4(mh, mx);
    }
#pragma unroll
    for (int o = 0; o < NOUT; ++o) {
#pragma unroll
        for (int off = 32; off > 0; off >>= 1)
            acc[o] += __shfl_down(acc[o], off, 64);
    }
    __shared__ float red[4][NOUT];
    __shared__ float c8[NOUT];
    if (lane == 0) {
#pragma unroll
        for (int o = 0; o < NOUT; ++o) red[w][o] = acc[o];
    }
    if (tid < NOUT) {                            // c inline (512 floats, L2)
        float cc = b3[tid];
#pragma unroll 8
        for (int s = 0; s < NS; ++s)
            cc += cp1[s * NOUT + tid] + cp2[s * NOUT + tid];
        c8[tid] = cc;
    }
    __syncthreads();

    const int u = tid >> 1, half = tid & 1, o0 = half * 4;
    const float4* Qp4 = (const float4*)Qpart;
    float4 q = f4z();
#pragma unroll 8
    for (int ub = 0; ub < 32; ++ub)
        q = add4(q, Qp4[((size_t)ub * UDIM + u) * 2 + half]);

    float4 cv = make_float4(c8[o0], c8[o0 + 1], c8[o0 + 2], c8[o0 + 3]);
    float4 pv = make_float4(
        red[0][o0 + 0] + red[1][o0 + 0] + red[2][o0 + 0] + red[3][o0 + 0],
        red[0][o0 + 1] + red[1][o0 + 1] + red[2][o0 + 1] + red[3][o0 + 1],
        red[0][o0 + 2] + red[1][o0 + 2] + red[2][o0 + 2] + red[3][o0 + 2],
        red[0][o0 + 3] + red[1][o0 + 3] + red[2][o0 + 3] + red[3][o0 + 3]);
    out[(size_t)t * 256 + tid] = add4(add4(pv, q), cv);
}

extern "C" void kernel_launch(void* const* d_in, const int* in_sizes, int n_in,
                              void* d_out, int out_size, void* d_ws, size_t ws_size,
                              hipStream_t stream) {
    const float* text_a = (const float*)d_in[0];
    const float* text_b = (const float*)d_in[1];
    const float* user   = (const float*)d_in[2];
    const float* W1 = (const float*)d_in[3];
    const float* b1 = (const float*)d_in[4];
    const float* W2 = (const float*)d_in[5];
    const float* b2 = (const float*)d_in[6];
    const float* W3 = (const float*)d_in[7];
    const float* b3 = (const float*)d_in[8];

    float* ws = (float*)d_ws;
    float* part1 = ws;                                  // 786432 floats
    float* part2 = part1 + (size_t)NS * NOUT * HIDN;    // 786432
    float* Mt    = part2 + (size_t)NS * NOUT * HIDN;    // 16384 (8x2048)
    float* Qpart = Mt + NOUT * 2048;                    // 32768 (32x128x8)
    float* cp1   = Qpart + 32 * UDIM * NOUT;            // 256
    float* cp2   = cp1 + NS * NOUT;                     // 256
    int*   ctr   = (int*)(cp2 + NS * NOUT);             // 1

    // K1: part1 = W3 @ W2 ; cp2 ; ctr = 0
    gemm_partial<<<dim3(GX, NS), 256, 0, stream>>>(W3, nullptr, W2, part1,
                                                   b2, cp2, user, Mt, Qpart,
                                                   ctr, 0);
    // K2: part2 = M2 @ W1 ; cp1 ; tail absorbs Mt reduce + Q projection
    gemm_partial<<<dim3(GX, NS), 256, 0, stream>>>(nullptr, part1, W1, part2,
                                                   b1, cp1, user, Mt, Qpart,
                                                   ctr, 1);
    // K3: out (c inline)
    k4_out<<<TDIM, 256, 0, stream>>>(text_a, text_b, Mt, Qpart, cp1, cp2, b3,
                                     (float4*)d_out);
}

// Round 13
// 72.755 us; speedup vs baseline: 1.2029x; 1.2029x over previous
//
#include <hip/hip_runtime.h>
#include <hip/hip_bf16.h>

// LinearCombiner: MLP has NO activation -> affine: out = M@x + c,
// M = W3@W2@W1 (8x3072), c = (W3@W2)@b1 + W3@b2 + b3, and
// x[t,u] = [min;max;user] separable -> out[t,u,o] = P[t,o]+Q[u,o]+c[o].
//
// Ledger: dispatch overhead ~3.9us each; R10 (4 dispatches) = 33.0us =
// work (~17.5) + 4 boundaries. R12's tail fusion was correct (absmax ok) but
// busy-spin at agent scope strangled streaming (450 GB/s, 87us). Fix: same
// decoupled-counter tail + s_sleep backoff polling. 3 dispatches:
//  K1 (24x32): part1 = W3@W2 k-slice partials + cp2 ; ctr = 0
//  K2 (24x32): self-reduce M2 slice (L2-hot), part2 = M2@W1 + cp1; then
//              release fetch_add; last 97 incrementers sleep-poll until all
//              768 landed, then run one R10-K3 item each:
//              0..63 Mt chunk reduce / 64..95 M_user chunk + user proj / 96 c
//  K3 (256):   out[t,u,:] = P[t](Mt) + sum_ub Qpart + cvec  (1MB write)

#define HIDN 3072
#define DIM 1024
#define NOUT 8
#define NS 32            // k-slices
#define KPS 96           // rows per slice
#define RPT 12           // rows per thread (KPS / 8 row-groups)
#define GX 24            // column groups of 128 cols
#define CPB 128          // cols per block (32 f4)
#define TDIM 256
#define UDIM 128
#define PF4 6144         // NOUT*HIDN/4 (f4 stride between slice partials)
#define NBLK2 768        // GX*NS
#define NTAIL 97         // 64 Mt + 32 Q + 1 c
#define TAIL0 (NBLK2 - NTAIL)

__device__ __forceinline__ float4 f4z() { return make_float4(0.f, 0.f, 0.f, 0.f); }
__device__ __forceinline__ float4 add4(float4 a, float4 b) {
    return make_float4(a.x + b.x, a.y + b.y, a.z + b.z, a.w + b.w);
}
__device__ __forceinline__ float dot4(float4 a, float4 b) {
    return a.x * b.x + a.y * b.y + a.z * b.z + a.w * b.w;
}

// fold cp[s][o] = sum_kk As[o][kk] * bvec[s*KPS+kk]  (32 lanes per o)
__device__ __forceinline__ void bias_slice_fold(const float* As,
                                                const float* __restrict__ bvec,
                                                float* __restrict__ cp,
                                                int s, int tid) {
    const int o = tid >> 5, k5 = tid & 31;
    float acc = 0.f;
#pragma unroll
    for (int j = 0; j < KPS / 32; ++j)
        acc += As[o * KPS + k5 + 32 * j] * bvec[s * KPS + k5 + 32 * j];
#pragma unroll
    for (int off = 16; off; off >>= 1) acc += __shfl_down(acc, off, 32);
    if (k5 == 0) cp[s * NOUT + o] = acc;
}

// tail item b in [0,64): Mt chunk reduce (64 f4)  [R10 k3_mid b<64 body]
__device__ __forceinline__ void tail_mt(const float4* __restrict__ p4,
                                        float* __restrict__ Mt,
                                        int b, int tid, float4* redls) {
    const int lane = tid & 63, w = tid >> 6;
    const int i4 = b * 64 + lane;                // [0,4096): o=i4>>9, h4=i4&511
    const int o = i4 >> 9, h4 = i4 & 511;
    float4 acc = f4z();
#pragma unroll
    for (int j = 0; j < 8; ++j)
        acc = add4(acc, p4[(size_t)(w * 8 + j) * PF4 + o * 768 + h4]);
    redls[w * 64 + lane] = acc;
    __syncthreads();
    if (w == 0) {
        float4 r = add4(add4(redls[lane], redls[64 + lane]),
                        add4(redls[128 + lane], redls[192 + lane]));
        ((float4*)Mt)[i4] = r;
    }
}

// tail item ub in [0,32): M_user chunk reduce + projection  [R10 k3_mid body]
__device__ __forceinline__ void tail_q(const float4* __restrict__ p4,
                                       const float* __restrict__ user,
                                       float* __restrict__ Qpart,
                                       int ub, int tid, float4* redls) {
    float4* mup = redls;                         // 256 f4
    float4* Mu4 = redls + 256;                   // 64 f4
    const int tgt = tid & 63, grp = tid >> 6;
    const int o = tgt >> 3, j4 = tgt & 7;
    float4 a = f4z();
#pragma unroll
    for (int j = 0; j < 8; ++j)
        a = add4(a, p4[(size_t)(grp * 8 + j) * PF4 + o * 768 + 512 + ub * 8 + j4]);
    mup[grp * 64 + tgt] = a;
    __syncthreads();
    if (tid < 64)
        Mu4[tid] = add4(add4(mup[tid], mup[64 + tid]),
                        add4(mup[128 + tid], mup[192 + tid]));
    __syncthreads();

    const int u = tid >> 1, o0 = (tid & 1) * 4;
    const float4* uv = (const float4*)user + (size_t)u * (DIM / 4) + ub * 8;
    float4 x8[8];
#pragma unroll
    for (int j = 0; j < 8; ++j) x8[j] = uv[j];
    float q[4];
#pragma unroll
    for (int oo = 0; oo < 4; ++oo) {
        float s = 0.f;
#pragma unroll
        for (int j = 0; j < 8; ++j) s += dot4(Mu4[(o0 + oo) * 8 + j], x8[j]);
        q[oo] = s;
    }
    ((float4*)Qpart)[((size_t)ub * UDIM + u) * 2 + (tid & 1)] =
        make_float4(q[0], q[1], q[2], q[3]);
}

// mode 0 (K1): A_rows read directly; zeroes ctr. mode 1 (K2): A slice
// self-reduced from part_in; sleep-polled decoupled tail absorbs old K3.
// Block: 96 rows x 128 cols. Thread: rq = tid>>5 (12 rows), c4 = tid&31.
__global__ __launch_bounds__(256) void gemm_partial(
    const float* __restrict__ A_rows, const float* __restrict__ part_in,
    const float* __restrict__ B, float* __restrict__ part_out,
    const float* __restrict__ bvec, float* __restrict__ cp,
    const float* __restrict__ user, const float* __restrict__ cp2ro,
    const float* __restrict__ b3, float* __restrict__ Mt,
    float* __restrict__ Qpart, float* __restrict__ cvec,
    int* __restrict__ ctr, int mode) {
    const int s = blockIdx.y, gx = blockIdx.x;
    const int tid = threadIdx.x;
    const int rq = tid >> 5, c4 = tid & 31;

    __shared__ float As[NOUT * KPS];          // 3 KB
    __shared__ float4 red[8 * NOUT * 32];     // 32 KB: [rq][o][c4]

    if (mode == 0) {
        if (s == 0 && gx == 0 && tid == 0) *ctr = 0;   // reset tail counter
        for (int i = tid; i < NOUT * KPS; i += 256)
            As[i] = A_rows[(i / KPS) * HIDN + s * KPS + (i % KPS)];
    } else {
        // As[o][kk] = sum_sp part_in[sp][o][s*KPS+kk]  (L2/L3-hot, f4)
        if (tid < NOUT * KPS / 4) {
            const int j4 = tid;
            const int o = j4 / (KPS / 4), kk4 = j4 % (KPS / 4);
            const float4* pp = (const float4*)(part_in + (size_t)o * HIDN
                                               + s * KPS) + kk4;
            float4 a = f4z();
#pragma unroll 8
            for (int sp = 0; sp < NS; ++sp)
                a = add4(a, pp[(size_t)sp * PF4]);
            ((float4*)As)[j4] = a;
        }
    }
    __syncthreads();
    if (gx == 0) bias_slice_fold(As, bvec, cp, s, tid);

    const int k0 = s * KPS + rq * RPT;
    const float4* Bp = (const float4*)(B + (size_t)k0 * HIDN) + gx * 32 + c4;

    float4 bv[RPT];                            // 12 hoisted loads, 12KB/wave
#pragma unroll
    for (int kk = 0; kk < RPT; ++kk) bv[kk] = Bp[(size_t)kk * (HIDN / 4)];

    float4 acc[NOUT];
#pragma unroll
    for (int o = 0; o < NOUT; ++o) acc[o] = f4z();
#pragma unroll
    for (int kk = 0; kk < RPT; ++kk) {
#pragma unroll
        for (int o = 0; o < NOUT; ++o) {
            float a = As[o * KPS + rq * RPT + kk];
            acc[o].x += a * bv[kk].x; acc[o].y += a * bv[kk].y;
            acc[o].z += a * bv[kk].z; acc[o].w += a * bv[kk].w;
        }
    }

    // cross-row-group reduce: red[rq][o][c4], then thread (o,c4) sums 8 rq
#pragma unroll
    for (int o = 0; o < NOUT; ++o) red[rq * 256 + o * 32 + c4] = acc[o];
    __syncthreads();
    {
        const int o = tid >> 5, cc = tid & 31;   // 256 threads = 8 o x 32 c4
        float4 r = f4z();
#pragma unroll
        for (int q = 0; q < 8; ++q) r = add4(r, red[q * 256 + o * 32 + cc]);
        *(float4*)(part_out + ((size_t)s * NOUT + o) * HIDN + gx * CPB + cc * 4) = r;
    }

    if (mode == 0) return;

    // ---- decoupled tail with s_sleep backoff (R12 fix: no hot spin) ----
    __shared__ int item_s;
    __syncthreads();                          // part_out store issued by all
    if (tid == 0) {
        // release: prior stores ordered before the increment
        int old = __hip_atomic_fetch_add(ctr, 1, __ATOMIC_ACQ_REL,
                                         __HIP_MEMORY_SCOPE_AGENT);
        int item = old - TAIL0;
        if (item >= 0) {
            while (__hip_atomic_load(ctr, __ATOMIC_ACQUIRE,
                                     __HIP_MEMORY_SCOPE_AGENT) < NBLK2) {
                __builtin_amdgcn_s_sleep(8);   // ~512 cyc; no coherence spam
            }
        }
        item_s = item;
    }
    __syncthreads();
    const int item = item_s;
    if (item < 0) return;
    __threadfence();                          // acquire side for data lines

    const float4* p4 = (const float4*)part_out;
    if (item < 64) {
        tail_mt(p4, Mt, item, tid, red);
    } else if (item < 96) {
        tail_q(p4, user, Qpart, item - 64, tid, red);
    } else {
        if (tid < NOUT) {                     // c = sum_s(cp1+cp2)+b3
            float cc = b3[tid];
#pragma unroll 8
            for (int s2 = 0; s2 < NS; ++s2)
                cc += cp[s2 * NOUT + tid] + cp2ro[s2 * NOUT + tid];
            cvec[tid] = cc;
        }
    }
}

// K3: out[t,u,:] = P[t] + sum_ub Qpart[ub][u] + c   (256 t-blocks) [R10 k4]
__global__ __launch_bounds__(256) void k4_out(
    const float* __restrict__ ta, const float* __restrict__ tb,
    const float* __restrict__ Mt, const float* __restrict__ Qpart,
    const float* __restrict__ cvec, float4* __restrict__ out) {
    const int t = blockIdx.x, tid = threadIdx.x;
    const int lane = tid & 63, w = tid >> 6;

    const float4* Mt4 = (const float4*)Mt;
    float4 a = ((const float4*)ta)[(size_t)t * (DIM / 4) + tid];
    float4 b = ((const float4*)tb)[(size_t)t * (DIM / 4) + tid];
    float4 mn = make_float4(fminf(a.x, b.x), fminf(a.y, b.y),
                            fminf(a.z, b.z), fminf(a.w, b.w));
    float4 mx = make_float4(fmaxf(a.x, b.x), fmaxf(a.y, b.y),
                            fmaxf(a.z, b.z), fmaxf(a.w, b.w));
    float acc[NOUT];
#pragma unroll
    for (int o = 0; o < NOUT; ++o) {
        float4 ml = Mt4[o * 512 + tid];          // dims 0..1023 (min half)
        float4 mh = Mt4[o * 512 + 256 + tid];    // dims 1024..2047 (max half)
        acc[o] = dot4(ml, mn) + dot4(mh, mx);
    }
#pragma unroll
    for (int o = 0; o < NOUT; ++o) {
#pragma unroll
        for (int off = 32; off > 0; off >>= 1)
            acc[o] += __shfl_down(acc[o], off, 64);
    }
    __shared__ float red[4][NOUT];
    if (lane == 0) {
#pragma unroll
        for (int o = 0; o < NOUT; ++o) red[w][o] = acc[o];
    }
    __syncthreads();

    const int u = tid >> 1, half = tid & 1, o0 = half * 4;
    const float4* Qp4 = (const float4*)Qpart;
    float4 q = f4z();
#pragma unroll 8
    for (int ub = 0; ub < 32; ++ub)
        q = add4(q, Qp4[((size_t)ub * UDIM + u) * 2 + half]);

    float4 cv = ((const float4*)cvec)[half];
    float4 pv = make_float4(
        red[0][o0 + 0] + red[1][o0 + 0] + red[2][o0 + 0] + red[3][o0 + 0],
        red[0][o0 + 1] + red[1][o0 + 1] + red[2][o0 + 1] + red[3][o0 + 1],
        red[0][o0 + 2] + red[1][o0 + 2] + red[2][o0 + 2] + red[3][o0 + 2],
        red[0][o0 + 3] + red[1][o0 + 3] + red[2][o0 + 3] + red[3][o0 + 3]);
    out[(size_t)t * 256 + tid] = add4(add4(pv, q), cv);
}

extern "C" void kernel_launch(void* const* d_in, const int* in_sizes, int n_in,
                              void* d_out, int out_size, void* d_ws, size_t ws_size,
                              hipStream_t stream) {
    const float* text_a = (const float*)d_in[0];
    const float* text_b = (const float*)d_in[1];
    const float* user   = (const float*)d_in[2];
    const float* W1 = (const float*)d_in[3];
    const float* b1 = (const float*)d_in[4];
    const float* W2 = (const float*)d_in[5];
    const float* b2 = (const float*)d_in[6];
    const float* W3 = (const float*)d_in[7];
    const float* b3 = (const float*)d_in[8];

    float* ws = (float*)d_ws;
    float* part1 = ws;                                  // 786432 floats
    float* part2 = part1 + (size_t)NS * NOUT * HIDN;    // 786432
    float* Mt    = part2 + (size_t)NS * NOUT * HIDN;    // 16384 (8x2048)
    float* Qpart = Mt + NOUT * 2048;                    // 32768 (32x128x8)
    float* cp1   = Qpart + 32 * UDIM * NOUT;            // 256
    float* cp2   = cp1 + NS * NOUT;                     // 256
    float* cvec  = cp2 + NS * NOUT;                     // 8
    int*   ctr   = (int*)(cvec + NOUT);                 // 1

    // K1: part1 = W3 @ W2 ; cp2 ; ctr = 0
    gemm_partial<<<dim3(GX, NS), 256, 0, stream>>>(
        W3, nullptr, W2, part1, b2, cp2,
        nullptr, nullptr, nullptr, nullptr, nullptr, nullptr, ctr, 0);
    // K2: part2 = M2 @ W1 ; cp1 ; tail: Mt reduce + Q projection + c
    gemm_partial<<<dim3(GX, NS), 256, 0, stream>>>(
        nullptr, part1, W1, part2, b1, cp1,
        user, cp2, b3, Mt, Qpart, cvec, ctr, 1);
    // K3: out
    k4_out<<<TDIM, 256, 0, stream>>>(text_a, text_b, Mt, Qpart, cvec,
                                     (float4*)d_out);
}

// Round 14
// 32.555 us; speedup vs baseline: 2.6882x; 2.2348x over previous
//
#include <hip/hip_runtime.h>
#include <hip/hip_bf16.h>

// LinearCombiner: MLP has NO activation -> affine: out = M@x + c,
// M = W3@W2@W1 (8x3072), c = (W3@W2)@b1 + W3@b2 + b3, and
// x[t,u] = [min;max;user] separable -> out[t,u,o] = P[t,o]+Q[u,o]+c[o].
//
// R10 structure verbatim (proven 33.0us; R12/R13 proved in-kernel cross-block
// sync is toxic on gfx950 — agent-scope atomics force cross-XCD L2 flushes):
//  K1 (24x32): part1 = W3@W2 k-slice partials + cp2
//  K2 (24x32): self-reduce M2 slice from part1 (L2-hot), part2 = M2@W1 + cp1
//  K3 (97):    Mt reduce / M_user chunk reduce + user proj / c
//  K4 (256):   P[t] from Mt + Q = sum Qpart + c -> out row (1MB)
//
// R14 change (ONLY): XCD-chunked block swizzle in the GEMMs. 768 blocks =
// 8 XCDs x 96; default round-robin makes every XCD touch every B-row ->
// interleaved DRAM pages. Swizzle gives XCD k the contiguous s-band
// [4k,4k+4) (4.7MB) -> per-XCD DRAM/L2 locality (T1, +10% HBM-bound m192).

#define HIDN 3072
#define DIM 1024
#define NOUT 8
#define NS 32            // k-slices
#define KPS 96           // rows per slice
#define RPT 12           // rows per thread (KPS / 8 row-groups)
#define GX 24            // column groups of 128 cols
#define CPB 128          // cols per block (32 f4)
#define TDIM 256
#define UDIM 128
#define PF4 6144         // NOUT*HIDN/4 (f4 stride between slice partials)

__device__ __forceinline__ float4 f4z() { return make_float4(0.f, 0.f, 0.f, 0.f); }
__device__ __forceinline__ float4 add4(float4 a, float4 b) {
    return make_float4(a.x + b.x, a.y + b.y, a.z + b.z, a.w + b.w);
}
__device__ __forceinline__ float dot4(float4 a, float4 b) {
    return a.x * b.x + a.y * b.y + a.z * b.z + a.w * b.w;
}

// fold cp[s][o] = sum_kk As[o][kk] * bvec[s*KPS+kk]  (32 lanes per o)
__device__ __forceinline__ void bias_slice_fold(const float* As,
                                                const float* __restrict__ bvec,
                                                float* __restrict__ cp,
                                                int s, int tid) {
    const int o = tid >> 5, k5 = tid & 31;
    float acc = 0.f;
#pragma unroll
    for (int j = 0; j < KPS / 32; ++j)
        acc += As[o * KPS + k5 + 32 * j] * bvec[s * KPS + k5 + 32 * j];
#pragma unroll
    for (int off = 16; off; off >>= 1) acc += __shfl_down(acc, off, 32);
    if (k5 == 0) cp[s * NOUT + o] = acc;
}

// mode 0: A_rows (8,HIDN) read directly. mode 1: A slice self-reduced from
// part_in. part_out[s][o][h] = sum_{k in slice s} A[o,k] * B[k,h]
// Block: 96 rows x 128 cols. Thread: rq = tid>>5 (12 rows), c4 = tid&31.
__global__ __launch_bounds__(256) void gemm_partial(
    const float* __restrict__ A_rows, const float* __restrict__ part_in,
    const float* __restrict__ B, float* __restrict__ part_out,
    const float* __restrict__ bvec, float* __restrict__ cp, int mode) {
    // ---- XCD-chunked swizzle: XCD k owns contiguous s-band [4k, 4k+4) ----
    const int orig = blockIdx.y * GX + blockIdx.x;        // hw linear id
    const int virt = (orig & 7) * 96 + (orig >> 3);       // bijective, 768=8*96
    const int s = virt / GX, gx = virt % GX;
    const int tid = threadIdx.x;
    const int rq = tid >> 5, c4 = tid & 31;

    __shared__ float As[NOUT * KPS];          // 3 KB
    __shared__ float4 red[8 * NOUT * 32];     // 32 KB: [rq][o][c4]

    if (mode == 0) {
        for (int i = tid; i < NOUT * KPS; i += 256)
            As[i] = A_rows[(i / KPS) * HIDN + s * KPS + (i % KPS)];
    } else {
        // As[o][kk] = sum_sp part_in[sp][o][s*KPS+kk]  (L2/L3-hot, f4)
        if (tid < NOUT * KPS / 4) {
            const int j4 = tid;
            const int o = j4 / (KPS / 4), kk4 = j4 % (KPS / 4);
            const float4* pp = (const float4*)(part_in + (size_t)o * HIDN
                                               + s * KPS) + kk4;
            float4 a = f4z();
#pragma unroll 8
            for (int sp = 0; sp < NS; ++sp)
                a = add4(a, pp[(size_t)sp * PF4]);
            ((float4*)As)[j4] = a;
        }
    }
    __syncthreads();
    if (gx == 0) bias_slice_fold(As, bvec, cp, s, tid);

    const int k0 = s * KPS + rq * RPT;
    const float4* Bp = (const float4*)(B + (size_t)k0 * HIDN) + gx * 32 + c4;

    float4 bv[RPT];                            // 12 hoisted loads, 12KB/wave
#pragma unroll
    for (int kk = 0; kk < RPT; ++kk) bv[kk] = Bp[(size_t)kk * (HIDN / 4)];

    float4 acc[NOUT];
#pragma unroll
    for (int o = 0; o < NOUT; ++o) acc[o] = f4z();
#pragma unroll
    for (int kk = 0; kk < RPT; ++kk) {
#pragma unroll
        for (int o = 0; o < NOUT; ++o) {
            float a = As[o * KPS + rq * RPT + kk];
            acc[o].x += a * bv[kk].x; acc[o].y += a * bv[kk].y;
            acc[o].z += a * bv[kk].z; acc[o].w += a * bv[kk].w;
        }
    }

    // cross-row-group reduce: red[rq][o][c4], then thread (o,c4) sums 8 rq
#pragma unroll
    for (int o = 0; o < NOUT; ++o) red[rq * 256 + o * 32 + c4] = acc[o];
    __syncthreads();
    {
        const int o = tid >> 5, cc = tid & 31;   // 256 threads = 8 o x 32 c4
        float4 r = f4z();
#pragma unroll
        for (int q = 0; q < 8; ++q) r = add4(r, red[q * 256 + o * 32 + cc]);
        *(float4*)(part_out + ((size_t)s * NOUT + o) * HIDN + gx * CPB + cc * 4) = r;
    }
}

// K3: b<64: Mt reduce ; b in [64,96): M_user chunk reduce + user projection ;
//     b==96: c.
__global__ __launch_bounds__(256) void k3_mid(
    const float* __restrict__ part2, const float* __restrict__ user,
    const float* __restrict__ cp1, const float* __restrict__ cp2,
    const float* __restrict__ b3, float* __restrict__ Mt,
    float* __restrict__ Qpart, float* __restrict__ cvec) {
    const int b = blockIdx.x, tid = threadIdx.x;
    const float4* p4 = (const float4*)part2;

    if (b < 64) {
        // Mt: 4096 f4 total; block owns 64 f4; 4 waves split 32 slices.
        const int lane = tid & 63, w = tid >> 6;
        const int i4 = b * 64 + lane;            // [0,4096): o = i4>>9, h4 = i4&511
        const int o = i4 >> 9, h4 = i4 & 511;
        float4 acc = f4z();
#pragma unroll
        for (int j = 0; j < 8; ++j)
            acc = add4(acc, p4[(size_t)(w * 8 + j) * PF4 + o * 768 + h4]);
        __shared__ float4 red2[4 * 64];
        red2[w * 64 + lane] = acc;
        __syncthreads();
        if (w == 0) {
            float4 r = add4(add4(red2[lane], red2[64 + lane]),
                            add4(red2[128 + lane], red2[192 + lane]));
            ((float4*)Mt)[i4] = r;
        }
        return;
    }

    if (b < 96) {
        // user chunk ub: cols4 [512+ub*8, +8) -> user dims [ub*32, +32)
        const int ub = b - 64;
        __shared__ float4 mup[4 * 64];
        __shared__ float4 Mu4[NOUT * 8];         // Mu[8][32] as f4
        const int tgt = tid & 63, grp = tid >> 6;
        const int o = tgt >> 3, j4 = tgt & 7;
        float4 a = f4z();
#pragma unroll
        for (int j = 0; j < 8; ++j)
            a = add4(a, p4[(size_t)(grp * 8 + j) * PF4 + o * 768 + 512 + ub * 8 + j4]);
        mup[grp * 64 + tgt] = a;
        __syncthreads();
        if (tid < 64)
            Mu4[tid] = add4(add4(mup[tid], mup[64 + tid]),
                            add4(mup[128 + tid], mup[192 + tid]));
        __syncthreads();

        const int u = tid >> 1, o0 = (tid & 1) * 4;
        const float4* uv = (const float4*)user + (size_t)u * (DIM / 4) + ub * 8;
        float4 x8[8];
#pragma unroll
        for (int j = 0; j < 8; ++j) x8[j] = uv[j];
        float q[4];
#pragma unroll
        for (int oo = 0; oo < 4; ++oo) {
            float s = 0.f;
#pragma unroll
            for (int j = 0; j < 8; ++j) s += dot4(Mu4[(o0 + oo) * 8 + j], x8[j]);
            q[oo] = s;
        }
        ((float4*)Qpart)[((size_t)ub * UDIM + u) * 2 + (tid & 1)] =
            make_float4(q[0], q[1], q[2], q[3]);
        return;
    }

    if (tid < NOUT) {                            // b == 96: c
        float cc = b3[tid];
#pragma unroll 8
        for (int s = 0; s < NS; ++s)
            cc += cp1[s * NOUT + tid] + cp2[s * NOUT + tid];
        cvec[tid] = cc;
    }
}

// K4: out[t,u,:] = P[t] + sum_ub Qpart[ub][u] + c   (256 t-blocks)
__global__ __launch_bounds__(256) void k4_out(
    const float* __restrict__ ta, const float* __restrict__ tb,
    const float* __restrict__ Mt, const float* __restrict__ Qpart,
    const float* __restrict__ cvec, float4* __restrict__ out) {
    const int t = blockIdx.x, tid = threadIdx.x;
    const int lane = tid & 63, w = tid >> 6;

    const float4* Mt4 = (const float4*)Mt;
    float4 a = ((const float4*)ta)[(size_t)t * (DIM / 4) + tid];
    float4 b = ((const float4*)tb)[(size_t)t * (DIM / 4) + tid];
    float4 mn = make_float4(fminf(a.x, b.x), fminf(a.y, b.y),
                            fminf(a.z, b.z), fminf(a.w, b.w));
    float4 mx = make_float4(fmaxf(a.x, b.x), fmaxf(a.y, b.y),
                            fmaxf(a.z, b.z), fmaxf(a.w, b.w));
    float acc[NOUT];
#pragma unroll
    for (int o = 0; o < NOUT; ++o) {
        float4 ml = Mt4[o * 512 + tid];          // dims 0..1023 (min half)
        float4 mh = Mt4[o * 512 + 256 + tid];    // dims 1024..2047 (max half)
        acc[o] = dot4(ml, mn) + dot4(mh, mx);
    }
#pragma unroll
    for (int o = 0; o < NOUT; ++o) {
#pragma unroll
        for (int off = 32; off > 0; off >>= 1)
            acc[o] += __shfl_down(acc[o], off, 64);
    }
    __shared__ float red[4][NOUT];
    if (lane == 0) {
#pragma unroll
        for (int o = 0; o < NOUT; ++o) red[w][o] = acc[o];
    }
    __syncthreads();

    const int u = tid >> 1, half = tid & 1, o0 = half * 4;
    const float4* Qp4 = (const float4*)Qpart;
    float4 q = f4z();
#pragma unroll 8
    for (int ub = 0; ub < 32; ++ub)
        q = add4(q, Qp4[((size_t)ub * UDIM + u) * 2 + half]);

    float4 cv = ((const float4*)cvec)[half];
    float4 pv = make_float4(
        red[0][o0 + 0] + red[1][o0 + 0] + red[2][o0 + 0] + red[3][o0 + 0],
        red[0][o0 + 1] + red[1][o0 + 1] + red[2][o0 + 1] + red[3][o0 + 1],
        red[0][o0 + 2] + red[1][o0 + 2] + red[2][o0 + 2] + red[3][o0 + 2],
        red[0][o0 + 3] + red[1][o0 + 3] + red[2][o0 + 3] + red[3][o0 + 3]);
    out[(size_t)t * 256 + tid] = add4(add4(pv, q), cv);
}

extern "C" void kernel_launch(void* const* d_in, const int* in_sizes, int n_in,
                              void* d_out, int out_size, void* d_ws, size_t ws_size,
                              hipStream_t stream) {
    const float* text_a = (const float*)d_in[0];
    const float* text_b = (const float*)d_in[1];
    const float* user   = (const float*)d_in[2];
    const float* W1 = (const float*)d_in[3];
    const float* b1 = (const float*)d_in[4];
    const float* W2 = (const float*)d_in[5];
    const float* b2 = (const float*)d_in[6];
    const float* W3 = (const float*)d_in[7];
    const float* b3 = (const float*)d_in[8];

    float* ws = (float*)d_ws;
    float* part1 = ws;                                  // 786432 floats
    float* part2 = part1 + (size_t)NS * NOUT * HIDN;    // 786432
    float* Mt    = part2 + (size_t)NS * NOUT * HIDN;    // 16384 (8x2048)
    float* Qpart = Mt + NOUT * 2048;                    // 32768 (32x128x8)
    float* cp1   = Qpart + 32 * UDIM * NOUT;            // 256
    float* cp2   = cp1 + NS * NOUT;                     // 256
    float* cvec  = cp2 + NS * NOUT;                     // 8

    // K1: part1 = W3 @ W2 ; cp2
    gemm_partial<<<dim3(GX, NS), 256, 0, stream>>>(W3, nullptr, W2, part1,
                                                   b2, cp2, 0);
    // K2: As = M2 slice (self-reduce from part1) ; part2 = M2 @ W1 ; cp1
    gemm_partial<<<dim3(GX, NS), 256, 0, stream>>>(nullptr, part1, W1, part2,
                                                   b1, cp1, 1);
    // K3: Mt reduce + Qpart projection + c
    k3_mid<<<97, 256, 0, stream>>>(part2, user, cp1, cp2, b3, Mt, Qpart, cvec);
    // K4: out
    k4_out<<<TDIM, 256, 0, stream>>>(text_a, text_b, Mt, Qpart, cvec,
                                     (float4*)d_out);
}